// Round 7
// baseline (259.865 us; speedup 1.0000x reference)
//
#include <hip/hip_runtime.h>
#include <hip/hip_bf16.h>

#define CHUNK 1024
#define RR 64          // dst ranges
#define PDEPTH 96      // LDS bin depth (packed words) per range per round
#define NSUB 16        // sub-blocks per range in fused build+aggregate
#define CAPE 2560      // LDS edge capacity per sub-block (mean 1568, +25 sigma)
#define SUBWMAX 128    // max dst nodes per sub-block
typedef unsigned int uint;
typedef unsigned short ushort;

typedef __bf16 bf16x8 __attribute__((ext_vector_type(8)));
typedef float  f32x4  __attribute__((ext_vector_type(4)));

__device__ __forceinline__ ushort f2bf(float f) {
    const uint u = __float_as_uint(f);
    return (ushort)((u + 0x7fffu + ((u >> 16) & 1u)) >> 16);  // RNE
}

// ---------- Fused Phase 0+A: even blocks = GEMM tile, odd = partition slice ----------
// The two phases are data-independent (feat,weight->h vs src,dst->staging,gcur);
// co-scheduling them fills complementary pipes (BW/MFMA vs LDS-atomics) and
// removes one dispatch + prep_w (W converted in-LDS per gemm block).
#define APITCH 136
#define WPITCH 132
#define SMEM_BYTES (128 * WPITCH * 2 + 64 * APITCH * 2)   // 51200 (>= partition's 25088)

__global__ __launch_bounds__(256, 3) void gemm_part(const float* __restrict__ feat,
                                                    const float* __restrict__ weight,
                                                    const int* __restrict__ src,
                                                    const int* __restrict__ dst,
                                                    int* __restrict__ gcur,
                                                    uint* __restrict__ staging,
                                                    ushort* __restrict__ h,
                                                    int cap, int nE, int M) {
    __shared__ __align__(16) char smem[SMEM_BYTES];
    const int t    = threadIdx.x;
    const int kind = blockIdx.x & 1;
    const int idx  = blockIdx.x >> 1;

    if (kind == 0) {
        // ================= GEMM tile =================
        const int row0 = idx * 64;
        if (row0 >= M) return;
        ushort* W_lds = (ushort*)smem;                          // [128][WPITCH]
        ushort* A_lds = (ushort*)(smem + 128 * WPITCH * 2);     // [64][APITCH]
        const int wave = t >> 6;
        const int lane = t & 63;
        const int quad = lane >> 4;
        const int nn   = lane & 15;

        // W transpose-convert: weight[k][n] f32 -> W_lds[n][k] bf16
#pragma unroll
        for (int p = 0; p < 16; ++p) {
            const int ii = p * 256 + t;          // 0..4095 float4-granules
            const int k  = ii >> 5;              // 0..127
            const int n4 = (ii & 31) * 4;
            const float4 w4 = *reinterpret_cast<const float4*>(weight + k * 128 + n4);
            W_lds[(n4 + 0) * WPITCH + k] = f2bf(w4.x);
            W_lds[(n4 + 1) * WPITCH + k] = f2bf(w4.y);
            W_lds[(n4 + 2) * WPITCH + k] = f2bf(w4.z);
            W_lds[(n4 + 3) * WPITCH + k] = f2bf(w4.w);
        }

        // Stage feat rows -> bf16 LDS tile [64][APITCH]
#pragma unroll
        for (int p = 0; p < 8; ++p) {
            const int ii  = p * 256 + t;         // 0..2047 float4-granules
            const int row = ii >> 5;
            const int c4  = (ii & 31) * 4;
            const int grow = row0 + row;
            float4 v = make_float4(0.f, 0.f, 0.f, 0.f);
            if (grow < M)
                v = *reinterpret_cast<const float4*>(&feat[(size_t)grow * 128 + c4]);
            const uint2 pk = make_uint2((uint)f2bf(v.x) | ((uint)f2bf(v.y) << 16),
                                        (uint)f2bf(v.z) | ((uint)f2bf(v.w) << 16));
            *reinterpret_cast<uint2*>(&A_lds[row * APITCH + c4]) = pk;
        }
        __syncthreads();

        union UA { uint4 u; bf16x8 b; };
        union UB { uint4 u; bf16x8 b; };
        UA afrag[4];
#pragma unroll
        for (int kc = 0; kc < 4; ++kc)
            afrag[kc].u = *reinterpret_cast<const uint4*>(
                &A_lds[(wave * 16 + nn) * APITCH + kc * 32 + quad * 8]);

        f32x4 acc[8];
#pragma unroll
        for (int ct = 0; ct < 8; ++ct) {
            UB bfr[4];
#pragma unroll
            for (int kc = 0; kc < 4; ++kc)
                bfr[kc].u = *reinterpret_cast<const uint4*>(
                    &W_lds[(ct * 16 + nn) * WPITCH + kc * 32 + quad * 8]);
            acc[ct] = (f32x4){0.f, 0.f, 0.f, 0.f};
#pragma unroll
            for (int kc = 0; kc < 4; ++kc)
                acc[ct] = __builtin_amdgcn_mfma_f32_16x16x32_bf16(
                    afrag[kc].b, bfr[kc].b, acc[ct], 0, 0, 0);
        }
        __syncthreads();   // all A reads done; reuse LDS for C

        // C/D layout: col = ct*16+nn, row_local = wave*16 + quad*4 + reg
#pragma unroll
        for (int ct = 0; ct < 8; ++ct) {
#pragma unroll
            for (int reg = 0; reg < 4; ++reg) {
                const int rl = wave * 16 + quad * 4 + reg;
                A_lds[rl * APITCH + ct * 16 + nn] = f2bf(acc[ct][reg]);
            }
        }
        __syncthreads();

        // Coalesced store: 4 x uint4 per thread
#pragma unroll
        for (int p = 0; p < 4; ++p) {
            const int ii  = p * 256 + t;         // 0..1023 uint4-granules
            const int row = ii >> 4;
            const int c16 = ii & 15;
            const int grow = row0 + row;
            if (grow < M) {
                const uint4 v = *reinterpret_cast<const uint4*>(&A_lds[row * APITCH + c16 * 8]);
                *reinterpret_cast<uint4*>(&h[(size_t)grow * 128 + c16 * 8]) = v;
            }
        }
    } else {
        // ================= partition slice =================
        // Packed staging word: src (17 bits) | local_dst (11 bits) << 17.
        uint (*bins)[PDEPTH] = (uint(*)[PDEPTH])smem;           // [RR][PDEPTH]
        int* cnt = (int*)(smem + RR * PDEPTH * 4);
        int* res = cnt + RR;
        const int nb = gridDim.x >> 1;
        const int N  = M;
        const int rounds = (nE + nb * 1024 - 1) / (nb * 1024);

        for (int rd = 0; rd < rounds; ++rd) {
            if (t < RR) cnt[t] = 0;
            __syncthreads();

            const int e4 = (rd * nb + idx) * 1024 + t * 4;
            int s[4], d[4];
            int nv = 0;
            if (e4 + 3 < nE) {
                const int4 s4 = *reinterpret_cast<const int4*>(src + e4);
                const int4 d4 = *reinterpret_cast<const int4*>(dst + e4);
                s[0] = s4.x; s[1] = s4.y; s[2] = s4.z; s[3] = s4.w;
                d[0] = d4.x; d[1] = d4.y; d[2] = d4.z; d[3] = d4.w;
                nv = 4;
            } else {
                for (int e = e4; e < nE; ++e) { s[nv] = src[e]; d[nv] = dst[e]; ++nv; }
            }
#pragma unroll
            for (int i = 0; i < 4; ++i) {
                if (i < nv) {
                    const int r  = (int)(((long long)d[i] * RR) / N);
                    const int lo = (int)(((long long)r * N + RR - 1) / RR);
                    const uint pk = (uint)s[i] | ((uint)(d[i] - lo) << 17);
                    const int pos = atomicAdd(&cnt[r], 1);
                    if (pos < PDEPTH) {
                        bins[r][pos] = pk;
                    } else {
                        const int gp = atomicAdd(&gcur[r], 1);
                        staging[(size_t)r * cap + gp] = pk;
                    }
                }
            }
            __syncthreads();
            if (t < RR) {
                int c = cnt[t];
                c = c < PDEPTH ? c : PDEPTH;
                cnt[t] = c;
                res[t] = (c > 0) ? atomicAdd(&gcur[t], c) : 0;
            }
            __syncthreads();
            {
                // wave-per-range copy-out: contiguous 4B*count bursts
                const int w    = t >> 6;
                const int lane = t & 63;
                for (int rr = w * 16; rr < w * 16 + 16; ++rr) {
                    const int c = cnt[rr];
                    const int b = res[rr];
                    uint* sp = staging + (size_t)rr * cap + b;
                    if (lane < c) sp[lane] = bins[rr][lane];
                    if (c > 64 && lane + 64 < c) sp[64 + lane] = bins[rr][64 + lane];
                }
            }
            __syncthreads();
        }
    }
}

// ---------- Fused Phase 1+B: per-sub-range CSR build in LDS + aggregate ----------
// (round-2 proven body: 83us) grid = RR*NSUB blocks of 512.
__global__ __launch_bounds__(512, 8) void build_agg(const uint* __restrict__ staging,
                                                    const int* __restrict__ gcur,
                                                    const ushort* __restrict__ h,
                                                    const float* __restrict__ bias,
                                                    float* __restrict__ out, int cap, int N) {
    __shared__ uint epack[CAPE];
    __shared__ int  csr_s[CAPE];
    __shared__ int  hist[SUBWMAX];
    __shared__ int  off_s[SUBWMAX];
    __shared__ int  cur_s[SUBWMAX];
    __shared__ int  sbuf[SUBWMAX];
    __shared__ int  scnt;

    const int t    = threadIdx.x;
    const int bid  = blockIdx.x;
    const int xcd  = bid & 7;
    const int i2   = bid >> 3;          // 0..127
    const int r    = xcd * 8 + (i2 >> 4);
    const int sub  = i2 & (NSUB - 1);

    const int lo   = (int)(((long long)r * N + RR - 1) / RR);
    const int hi   = (int)(((long long)(r + 1) * N + RR - 1) / RR);
    const int W    = hi - lo;
    const int SUBW = (W + NSUB - 1) / NSUB;
    const int nlo  = sub * SUBW;
    const int nhi  = min(W, nlo + SUBW);
    const int SW   = nhi - nlo;
    if (SW <= 0) return;                 // uniform per block

    const int  cnt_r = gcur[r];
    const uint* ep   = staging + (size_t)r * cap;
    const int  lane  = t & 63;

    if (t == 0) scnt = 0;
    if (t < SUBWMAX) hist[t] = 0;
    __syncthreads();

    // -- filter my dst-window out of the range's staging (ballot append) --
    const int nall = (cnt_r + 511) & ~511;
    for (int i = t; i < nall; i += 512) {
        uint v = 0;
        bool keep = false;
        if (i < cnt_r) {
            v = ep[i];
            const int ld = (int)(v >> 17);
            keep = (ld >= nlo) && (ld < nhi);
        }
        const unsigned long long m = __ballot(keep);
        const int tot = __popcll(m);
        if (tot) {
            int wb = 0;
            if (lane == 0) wb = atomicAdd(&scnt, tot);
            wb = __shfl(wb, 0);
            if (keep) {
                const int p = wb + __popcll(m & ((1ull << lane) - 1ull));
                if (p < CAPE) epack[p] = v;
            }
        }
    }
    __syncthreads();
    const int ne = min(scnt, CAPE);

    // -- histogram --
    for (int i = t; i < ne; i += 512)
        atomicAdd(&hist[(int)(epack[i] >> 17) - nlo], 1);
    __syncthreads();

    // -- exclusive scan over SUBWMAX entries --
    int v0 = 0;
    if (t < SUBWMAX) { v0 = hist[t]; sbuf[t] = v0; }
    __syncthreads();
    for (int d = 1; d < SUBWMAX; d <<= 1) {
        int x = 0;
        if (t < SUBWMAX && t >= d) x = sbuf[t - d];
        __syncthreads();
        if (t < SUBWMAX) sbuf[t] += x;
        __syncthreads();
    }
    if (t < SUBWMAX) { const int e = sbuf[t] - v0; off_s[t] = e; cur_s[t] = e; }
    __syncthreads();

    // -- scatter into LDS CSR --
    for (int i = t; i < ne; i += 512) {
        const uint v  = epack[i];
        const int ld  = (int)(v >> 17) - nlo;
        const int pos = atomicAdd(&cur_s[ld], 1);
        csr_s[pos] = (int)(v & 0x1FFFFu);
    }
    __syncthreads();

    // -- aggregate: one node per wave, csr from LDS --
    const int wv  = t >> 6;
    const int q   = lane >> 4;
    const int sbl = lane & 15;

#define UNPACK_ADD(rr)                                             \
    do {                                                           \
        acc[0] += __uint_as_float(((rr).x & 0xffffu) << 16);       \
        acc[1] += __uint_as_float((rr).x & 0xffff0000u);           \
        acc[2] += __uint_as_float(((rr).y & 0xffffu) << 16);       \
        acc[3] += __uint_as_float((rr).y & 0xffff0000u);           \
        acc[4] += __uint_as_float(((rr).z & 0xffffu) << 16);       \
        acc[5] += __uint_as_float((rr).z & 0xffff0000u);           \
        acc[6] += __uint_as_float(((rr).w & 0xffffu) << 16);       \
        acc[7] += __uint_as_float((rr).w & 0xffff0000u);           \
    } while (0)

    for (int n = wv; n < SW; n += 8) {
        const int start = off_s[n];
        const int dg    = hist[n];
        const int end   = start + dg;

        float acc[8];
#pragma unroll
        for (int k = 0; k < 8; ++k) acc[k] = 0.0f;

        int j = start;
        for (; j + 15 < end; j += 16) {
            int s[4];
#pragma unroll
            for (int k = 0; k < 4; ++k) s[k] = csr_s[j + q + 4 * k];
            uint4 rg[4];
#pragma unroll
            for (int k = 0; k < 4; ++k)
                rg[k] = *reinterpret_cast<const uint4*>(h + (size_t)s[k] * 128 + sbl * 8);
#pragma unroll
            for (int k = 0; k < 4; ++k) UNPACK_ADD(rg[k]);
        }
        for (; j + 3 < end; j += 4) {
            const int s = csr_s[j + q];
            const uint4 rr = *reinterpret_cast<const uint4*>(h + (size_t)s * 128 + sbl * 8);
            UNPACK_ADD(rr);
        }
        const int rem = end - j;
        if (q < rem) {
            const int s = csr_s[j + q];
            const uint4 rr = *reinterpret_cast<const uint4*>(h + (size_t)s * 128 + sbl * 8);
            UNPACK_ADD(rr);
        }

#pragma unroll
        for (int k = 0; k < 8; ++k) {
            acc[k] += __shfl_xor(acc[k], 16, 64);
            acc[k] += __shfl_xor(acc[k], 32, 64);
        }

        if (lane < 16) {
            const float nm = rsqrtf(fmaxf((float)dg, 1.0f));
            const float4 b0 = *reinterpret_cast<const float4*>(bias + sbl * 8 + 0);
            const float4 b1 = *reinterpret_cast<const float4*>(bias + sbl * 8 + 4);
            float4 o0, o1;
            o0.x = fmaf(acc[0], nm, b0.x);
            o0.y = fmaf(acc[1], nm, b0.y);
            o0.z = fmaf(acc[2], nm, b0.z);
            o0.w = fmaf(acc[3], nm, b0.w);
            o1.x = fmaf(acc[4], nm, b1.x);
            o1.y = fmaf(acc[5], nm, b1.y);
            o1.z = fmaf(acc[6], nm, b1.z);
            o1.w = fmaf(acc[7], nm, b1.w);
            const size_t gnode = (size_t)(lo + nlo + n);
            *reinterpret_cast<float4*>(out + gnode * 128 + sbl * 8 + 0) = o0;
            *reinterpret_cast<float4*>(out + gnode * 128 + sbl * 8 + 4) = o1;
        }
    }
#undef UNPACK_ADD
}

// ---------- Fallback path (ws too small) ----------
__global__ void hist_simple(const int* __restrict__ dst, int* __restrict__ deg, int nE) {
    int e = blockIdx.x * blockDim.x + threadIdx.x;
    if (e < nE) atomicAdd(&deg[dst[e]], 1);
}
__global__ void bucket_simple(const int* __restrict__ src, const int* __restrict__ dst,
                              int* __restrict__ cur, int* __restrict__ csr, int nE) {
    int e = blockIdx.x * blockDim.x + threadIdx.x;
    if (e < nE) {
        int pos = atomicAdd(&cur[dst[e]], 1);
        csr[pos] = src[e];
    }
}
__global__ __launch_bounds__(256) void scan_chunks(const int* __restrict__ deg,
                                                   int* __restrict__ off,
                                                   int* __restrict__ partials, int N) {
    __shared__ int sums[256];
    const int b = blockIdx.x, t = threadIdx.x;
    const int base = b * CHUNK + t * 4;
    int v[4];
#pragma unroll
    for (int i = 0; i < 4; ++i) v[i] = (base + i < N) ? deg[base + i] : 0;
    const int s = v[0] + v[1] + v[2] + v[3];
    sums[t] = s;
    __syncthreads();
    for (int d = 1; d < 256; d <<= 1) {
        int x = (t >= d) ? sums[t - d] : 0;
        __syncthreads();
        sums[t] += x;
        __syncthreads();
    }
    const int excl = sums[t] - s;
    if (t == 255) partials[b] = sums[255];
    int run = excl;
#pragma unroll
    for (int i = 0; i < 4; ++i) {
        if (base + i < N) off[base + i] = run;
        run += v[i];
    }
}
__global__ __launch_bounds__(256) void scan_partials(int* partials, int P) {
    __shared__ int buf[256];
    const int t = threadIdx.x;
    if (P <= 256) {
        const int v = (t < P) ? partials[t] : 0;
        buf[t] = v;
        __syncthreads();
        for (int d = 1; d < 256; d <<= 1) {
            int x = (t >= d) ? buf[t - d] : 0;
            __syncthreads();
            buf[t] += x;
            __syncthreads();
        }
        if (t < P) partials[t] = buf[t] - v;
    } else if (t == 0) {
        int acc = 0;
        for (int i = 0; i < P; ++i) { int v = partials[i]; partials[i] = acc; acc += v; }
    }
}
__global__ void add_base(int* __restrict__ off, int* __restrict__ cur,
                         const int* __restrict__ partials, int N) {
    int i = blockIdx.x * blockDim.x + threadIdx.x;
    if (i < N) {
        int o = off[i] + partials[i >> 10];
        off[i] = o;
        cur[i] = o;
    }
}
__global__ __launch_bounds__(256) void aggregate_f32(const float* __restrict__ feat,
                                                     const int* __restrict__ csr,
                                                     const int* __restrict__ off,
                                                     const int* __restrict__ deg,
                                                     float* __restrict__ out, int N) {
    const int node = (blockIdx.x * blockDim.x + threadIdx.x) >> 6;
    if (node >= N) return;
    const int lane = threadIdx.x & 63;
    const int start = off[node];
    const int end   = start + deg[node];
    const float2* feat2 = reinterpret_cast<const float2*>(feat);
    float ax = 0.0f, ay = 0.0f;
    for (int j = start; j < end; ++j) {
        const float2 v = feat2[(size_t)csr[j] * 64 + lane];
        ax += v.x;
        ay += v.y;
    }
    reinterpret_cast<float2*>(out)[(size_t)node * 64 + lane] = make_float2(ax, ay);
}
__global__ __launch_bounds__(256) void gemm_norm(const float* agg,
                                                 const float* __restrict__ weight,
                                                 const float* __restrict__ bias,
                                                 const int* __restrict__ deg,
                                                 float* out, int M) {
    __shared__ float As[64][68];
    __shared__ float Wc[64][128];
    const int t  = threadIdx.x;
    const int tx = t & 15;
    const int ty = t >> 4;
    const int row0 = blockIdx.x * 64;
    float acc[4][8];
#pragma unroll
    for (int i = 0; i < 4; ++i)
#pragma unroll
        for (int j = 0; j < 8; ++j) acc[i][j] = 0.0f;
    for (int c = 0; c < 2; ++c) {
        if (c) __syncthreads();
        {
            const int k4 = (t & 15) * 4;
            const int rbase = t >> 4;
#pragma unroll
            for (int p = 0; p < 4; ++p) {
                const int rr = rbase + p * 16;
                const int grow = row0 + rr;
                float4 v = make_float4(0.f, 0.f, 0.f, 0.f);
                if (grow < M)
                    v = *reinterpret_cast<const float4*>(&agg[(size_t)grow * 128 + c * 64 + k4]);
                *reinterpret_cast<float4*>(&As[rr][k4]) = v;
            }
        }
        {
#pragma unroll
            for (int p = 0; p < 8; ++p) {
                const int idx = (p * 256 + t) * 4;
                const int kk = idx >> 7;
                const int j = idx & 127;
                *reinterpret_cast<float4*>(&Wc[kk][j]) =
                    *reinterpret_cast<const float4*>(&weight[(c * 64 + kk) * 128 + j]);
            }
        }
        __syncthreads();
#pragma unroll 8
        for (int k = 0; k < 64; ++k) {
            float a[4];
#pragma unroll
            for (int i = 0; i < 4; ++i) a[i] = As[ty * 4 + i][k];
            const float4 b0 = *reinterpret_cast<const float4*>(&Wc[k][tx * 8 + 0]);
            const float4 b1 = *reinterpret_cast<const float4*>(&Wc[k][tx * 8 + 4]);
            const float b[8] = {b0.x, b0.y, b0.z, b0.w, b1.x, b1.y, b1.z, b1.w};
#pragma unroll
            for (int i = 0; i < 4; ++i)
#pragma unroll
                for (int j = 0; j < 8; ++j)
                    acc[i][j] = fmaf(a[i], b[j], acc[i][j]);
        }
    }
    float bcol[8];
#pragma unroll
    for (int j = 0; j < 8; ++j) bcol[j] = bias[tx * 8 + j];
#pragma unroll
    for (int i = 0; i < 4; ++i) {
        const int grow = row0 + ty * 4 + i;
        if (grow < M) {
            const float nm = rsqrtf(fmaxf((float)deg[grow], 1.0f));
            float4 o0, o1;
            o0.x = fmaf(acc[i][0], nm, bcol[0]);
            o0.y = fmaf(acc[i][1], nm, bcol[1]);
            o0.z = fmaf(acc[i][2], nm, bcol[2]);
            o0.w = fmaf(acc[i][3], nm, bcol[3]);
            o1.x = fmaf(acc[i][4], nm, bcol[4]);
            o1.y = fmaf(acc[i][5], nm, bcol[5]);
            o1.z = fmaf(acc[i][6], nm, bcol[6]);
            o1.w = fmaf(acc[i][7], nm, bcol[7]);
            *reinterpret_cast<float4*>(&out[(size_t)grow * 128 + tx * 8 + 0]) = o0;
            *reinterpret_cast<float4*>(&out[(size_t)grow * 128 + tx * 8 + 4]) = o1;
        }
    }
}

extern "C" void kernel_launch(void* const* d_in, const int* in_sizes, int n_in,
                              void* d_out, int out_size, void* d_ws, size_t ws_size,
                              hipStream_t stream) {
    const float* feat   = (const float*)d_in[0];
    const int*   src    = (const int*)d_in[1];
    const int*   dst    = (const int*)d_in[2];
    const float* weight = (const float*)d_in[3];
    const float* bias   = (const float*)d_in[4];
    float* out = (float*)d_out;

    const int nE = in_sizes[1];
    const int M  = in_sizes[0] / 128;
    const int P  = (M + CHUNK - 1) / CHUNK;

    // main-path ws: gcur[RR] | staging uint[RR*cap] | h ushort[M*128]
    int*    gcur    = (int*)d_ws;
    uint*   staging = (uint*)(gcur + RR);
    const int cap = (((nE + RR - 1) / RR + 8192) + 3) & ~3;
    ushort* h = (ushort*)(staging + (size_t)RR * cap);
    const size_t need = (size_t)RR * 4 + (size_t)RR * cap * 4 + (size_t)M * 128 * 2;

    if (ws_size >= need && M <= 102400) {
        const int gblocks = (M + 63) / 64;
        const int pblocks = 1600;
        const int half    = gblocks > pblocks ? gblocks : pblocks;
        hipMemsetAsync(gcur, 0, RR * sizeof(int), stream);
        gemm_part<<<2 * half, 256, 0, stream>>>(feat, weight, src, dst,
                                                gcur, staging, h, cap, nE, M);
        build_agg<<<RR * NSUB, 512, 0, stream>>>(staging, gcur, h, bias, out, cap, M);
    } else {
        int* degi     = (int*)d_ws;
        int* off      = degi + M;
        int* cur      = off + M;
        int* partials = cur + M;
        int* csr      = partials + 256;
        hipMemsetAsync(degi, 0, (size_t)M * sizeof(int), stream);
        hist_simple<<<(nE + 255) / 256, 256, 0, stream>>>(dst, degi, nE);
        scan_chunks<<<P, 256, 0, stream>>>(degi, off, partials, M);
        scan_partials<<<1, 256, 0, stream>>>(partials, P);
        add_base<<<(M + 255) / 256, 256, 0, stream>>>(off, cur, partials, M);
        bucket_simple<<<(nE + 255) / 256, 256, 0, stream>>>(src, dst, cur, csr, nE);
        aggregate_f32<<<(M + 3) / 4, 256, 0, stream>>>(feat, csr, off, degi, out, M);
        gemm_norm<<<(M + 63) / 64, 256, 0, stream>>>(out, weight, bias, degi, out, M);
    }
}

// Round 8
// 229.373 us; speedup vs baseline: 1.1329x; 1.1329x over previous
//
#include <hip/hip_runtime.h>
#include <hip/hip_bf16.h>

#define CHUNK 1024
#define RR 64          // dst ranges
#define PDEPTH 96      // LDS bin depth (packed words) per range per round
#define NSUB 16        // sub-blocks per range in fused build+aggregate
#define CAPE 2560      // LDS edge capacity per sub-block (mean 1568, +25 sigma)
#define SUBWMAX 128    // max dst nodes per sub-block
typedef unsigned int uint;
typedef unsigned short ushort;

typedef __bf16 bf16x8 __attribute__((ext_vector_type(8)));
typedef float  f32x4  __attribute__((ext_vector_type(4)));

__device__ __forceinline__ ushort f2bf(float f) {
    const uint u = __float_as_uint(f);
    return (ushort)((u + 0x7fffu + ((u >> 16) & 1u)) >> 16);  // RNE
}

// ---------- Phase 0: single-pass partition into RR dst-ranges ----------
// Packed staging word: src (17 bits) | local_dst (11 bits) << 17.
__global__ __launch_bounds__(256) void partition64(const int* __restrict__ src,
                                                   const int* __restrict__ dst,
                                                   int* __restrict__ gcur,
                                                   uint* __restrict__ staging,
                                                   int cap, int nE, int N) {
    __shared__ uint bins[RR][PDEPTH];
    __shared__ int cnt[RR];
    __shared__ int res[RR];
    const int t  = threadIdx.x;
    const int nb = gridDim.x;
    const int rounds = (nE + nb * 1024 - 1) / (nb * 1024);

    for (int rd = 0; rd < rounds; ++rd) {
        if (t < RR) cnt[t] = 0;
        __syncthreads();

        const int e4 = (rd * nb + blockIdx.x) * 1024 + t * 4;
        int s[4], d[4];
        int nv = 0;
        if (e4 + 3 < nE) {
            const int4 s4 = *reinterpret_cast<const int4*>(src + e4);
            const int4 d4 = *reinterpret_cast<const int4*>(dst + e4);
            s[0] = s4.x; s[1] = s4.y; s[2] = s4.z; s[3] = s4.w;
            d[0] = d4.x; d[1] = d4.y; d[2] = d4.z; d[3] = d4.w;
            nv = 4;
        } else {
            for (int e = e4; e < nE; ++e) { s[nv] = src[e]; d[nv] = dst[e]; ++nv; }
        }
#pragma unroll
        for (int i = 0; i < 4; ++i) {
            if (i < nv) {
                const int r  = (int)(((long long)d[i] * RR) / N);
                const int lo = (int)(((long long)r * N + RR - 1) / RR);
                const uint pk = (uint)s[i] | ((uint)(d[i] - lo) << 17);
                const int pos = atomicAdd(&cnt[r], 1);
                if (pos < PDEPTH) {
                    bins[r][pos] = pk;
                } else {
                    const int gp = atomicAdd(&gcur[r], 1);
                    staging[(size_t)r * cap + gp] = pk;
                }
            }
        }
        __syncthreads();
        if (t < RR) {
            int c = cnt[t];
            c = c < PDEPTH ? c : PDEPTH;
            cnt[t] = c;
            res[t] = (c > 0) ? atomicAdd(&gcur[t], c) : 0;
        }
        __syncthreads();
        {
            // wave-per-range copy-out: contiguous 4B*count bursts
            const int w    = t >> 6;
            const int lane = t & 63;
            for (int rr = w * 16; rr < w * 16 + 16; ++rr) {
                const int c = cnt[rr];
                const int b = res[rr];
                uint* sp = staging + (size_t)rr * cap + b;
                if (lane < c) sp[lane] = bins[rr][lane];
                if (c > 64 && lane + 64 < c) sp[64 + lane] = bins[rr][64 + lane];
            }
        }
        __syncthreads();
    }
}

// ---------- W prep: wt[n][k] = bf16(W[k][n]); block 0 also zeroes gcur ----------
__global__ __launch_bounds__(256) void prep_w(const float* __restrict__ w,
                                              ushort* __restrict__ wt,
                                              int* __restrict__ gcur) {
    if (blockIdx.x == 0 && threadIdx.x < RR) gcur[threadIdx.x] = 0;
    const int idx = blockIdx.x * 256 + threadIdx.x;  // 0..16383
    const int k = idx >> 7;
    const int n = idx & 127;
    wt[n * 128 + k] = f2bf(w[k * 128 + n]);
}

// ---------- Phase A: h = feat @ W via bf16 MFMA, output bf16 ----------
// A-fragments loaded DIRECTLY from global (8 consecutive floats of one row
// per kc — a wave's loads tile 16 rows x one 128B line, fully coalesced).
// LDS holds only W (33.8KB); C epilogue reuses the W buffer => 4 blocks/CU.
#define WPITCH 132
#define CPITCH 136
__global__ __launch_bounds__(256, 4) void gemm_mfma(const float* __restrict__ feat,
                                                    const ushort* __restrict__ wt,
                                                    ushort* __restrict__ h, int M) {
    __shared__ ushort W_lds[128 * WPITCH];     // 33792 B; reused for C (64*CPITCH=17408)
    const int t    = threadIdx.x;
    const int wave = t >> 6;
    const int lane = t & 63;
    const int quad = lane >> 4;
    const int nn   = lane & 15;
    const int row0 = blockIdx.x * 64;

    // Stage W^T -> LDS (coalesced 16B copies)
#pragma unroll
    for (int p = 0; p < 8; ++p) {
        const int idx = p * 256 + t;          // 0..2047 chunks of 8 ushorts
        const int row = idx >> 4;             // 0..127
        const int c8  = (idx & 15) * 8;
        *reinterpret_cast<uint4*>(&W_lds[row * WPITCH + c8]) =
            *reinterpret_cast<const uint4*>(wt + row * 128 + c8);
    }

    // A fragments straight from global: row = row0 + wave*16 + nn,
    // cols kc*32 + quad*8 .. +7  (two float4 loads per kc, cvt in-register)
    union UA { uint4 u; bf16x8 b; };
    union UB { uint4 u; bf16x8 b; };
    UA afrag[4];
    const int arow = row0 + wave * 16 + nn;
    const bool rowok = arow < M;
    const float* ap = feat + (size_t)arow * 128 + quad * 8;
#pragma unroll
    for (int kc = 0; kc < 4; ++kc) {
        float4 lo = make_float4(0.f, 0.f, 0.f, 0.f);
        float4 hi = lo;
        if (rowok) {
            lo = *reinterpret_cast<const float4*>(ap + kc * 32 + 0);
            hi = *reinterpret_cast<const float4*>(ap + kc * 32 + 4);
        }
        afrag[kc].u = make_uint4((uint)f2bf(lo.x) | ((uint)f2bf(lo.y) << 16),
                                 (uint)f2bf(lo.z) | ((uint)f2bf(lo.w) << 16),
                                 (uint)f2bf(hi.x) | ((uint)f2bf(hi.y) << 16),
                                 (uint)f2bf(hi.z) | ((uint)f2bf(hi.w) << 16));
    }
    __syncthreads();   // W_lds ready

    f32x4 acc[8];
#pragma unroll
    for (int ct = 0; ct < 8; ++ct) {
        UB bfr[4];
#pragma unroll
        for (int kc = 0; kc < 4; ++kc)
            bfr[kc].u = *reinterpret_cast<const uint4*>(
                &W_lds[(ct * 16 + nn) * WPITCH + kc * 32 + quad * 8]);
        acc[ct] = (f32x4){0.f, 0.f, 0.f, 0.f};
#pragma unroll
        for (int kc = 0; kc < 4; ++kc)
            acc[ct] = __builtin_amdgcn_mfma_f32_16x16x32_bf16(
                afrag[kc].b, bfr[kc].b, acc[ct], 0, 0, 0);
    }
    __syncthreads();   // all W reads done; reuse LDS for C

    // C/D layout: col = ct*16+nn, row_local = wave*16 + quad*4 + reg
#pragma unroll
    for (int ct = 0; ct < 8; ++ct) {
#pragma unroll
        for (int reg = 0; reg < 4; ++reg) {
            const int rl = wave * 16 + quad * 4 + reg;
            W_lds[rl * CPITCH + ct * 16 + nn] = f2bf(acc[ct][reg]);
        }
    }
    __syncthreads();

    // Coalesced store: 4 x uint4 per thread
#pragma unroll
    for (int p = 0; p < 4; ++p) {
        const int idx = p * 256 + t;          // 0..1023 uint4-granules
        const int row = idx >> 4;
        const int c16 = idx & 15;
        const int grow = row0 + row;
        if (grow < M) {
            const uint4 v = *reinterpret_cast<const uint4*>(&W_lds[row * CPITCH + c16 * 8]);
            *reinterpret_cast<uint4*>(&h[(size_t)grow * 128 + c16 * 8]) = v;
        }
    }
}

// ---------- Fused Phase 1+B: per-sub-range CSR build in LDS + aggregate ----------
// (round-2 proven body: 83us) grid = RR*NSUB blocks of 512.
__global__ __launch_bounds__(512, 8) void build_agg(const uint* __restrict__ staging,
                                                    const int* __restrict__ gcur,
                                                    const ushort* __restrict__ h,
                                                    const float* __restrict__ bias,
                                                    float* __restrict__ out, int cap, int N) {
    __shared__ uint epack[CAPE];
    __shared__ int  csr_s[CAPE];
    __shared__ int  hist[SUBWMAX];
    __shared__ int  off_s[SUBWMAX];
    __shared__ int  cur_s[SUBWMAX];
    __shared__ int  sbuf[SUBWMAX];
    __shared__ int  scnt;

    const int t    = threadIdx.x;
    const int bid  = blockIdx.x;
    const int xcd  = bid & 7;
    const int i2   = bid >> 3;          // 0..127
    const int r    = xcd * 8 + (i2 >> 4);
    const int sub  = i2 & (NSUB - 1);

    const int lo   = (int)(((long long)r * N + RR - 1) / RR);
    const int hi   = (int)(((long long)(r + 1) * N + RR - 1) / RR);
    const int W    = hi - lo;
    const int SUBW = (W + NSUB - 1) / NSUB;
    const int nlo  = sub * SUBW;
    const int nhi  = min(W, nlo + SUBW);
    const int SW   = nhi - nlo;
    if (SW <= 0) return;                 // uniform per block

    const int  cnt_r = gcur[r];
    const uint* ep   = staging + (size_t)r * cap;
    const int  lane  = t & 63;

    if (t == 0) scnt = 0;
    if (t < SUBWMAX) hist[t] = 0;
    __syncthreads();

    // -- filter my dst-window out of the range's staging (ballot append) --
    const int nall = (cnt_r + 511) & ~511;
    for (int i = t; i < nall; i += 512) {
        uint v = 0;
        bool keep = false;
        if (i < cnt_r) {
            v = ep[i];
            const int ld = (int)(v >> 17);
            keep = (ld >= nlo) && (ld < nhi);
        }
        const unsigned long long m = __ballot(keep);
        const int tot = __popcll(m);
        if (tot) {
            int wb = 0;
            if (lane == 0) wb = atomicAdd(&scnt, tot);
            wb = __shfl(wb, 0);
            if (keep) {
                const int p = wb + __popcll(m & ((1ull << lane) - 1ull));
                if (p < CAPE) epack[p] = v;
            }
        }
    }
    __syncthreads();
    const int ne = min(scnt, CAPE);

    // -- histogram --
    for (int i = t; i < ne; i += 512)
        atomicAdd(&hist[(int)(epack[i] >> 17) - nlo], 1);
    __syncthreads();

    // -- exclusive scan over SUBWMAX entries --
    int v0 = 0;
    if (t < SUBWMAX) { v0 = hist[t]; sbuf[t] = v0; }
    __syncthreads();
    for (int d = 1; d < SUBWMAX; d <<= 1) {
        int x = 0;
        if (t < SUBWMAX && t >= d) x = sbuf[t - d];
        __syncthreads();
        if (t < SUBWMAX) sbuf[t] += x;
        __syncthreads();
    }
    if (t < SUBWMAX) { const int e = sbuf[t] - v0; off_s[t] = e; cur_s[t] = e; }
    __syncthreads();

    // -- scatter into LDS CSR --
    for (int i = t; i < ne; i += 512) {
        const uint v  = epack[i];
        const int ld  = (int)(v >> 17) - nlo;
        const int pos = atomicAdd(&cur_s[ld], 1);
        csr_s[pos] = (int)(v & 0x1FFFFu);
    }
    __syncthreads();

    // -- aggregate: one node per wave, csr from LDS --
    const int wv  = t >> 6;
    const int q   = lane >> 4;
    const int sbl = lane & 15;

#define UNPACK_ADD(rr)                                             \
    do {                                                           \
        acc[0] += __uint_as_float(((rr).x & 0xffffu) << 16);       \
        acc[1] += __uint_as_float((rr).x & 0xffff0000u);           \
        acc[2] += __uint_as_float(((rr).y & 0xffffu) << 16);       \
        acc[3] += __uint_as_float((rr).y & 0xffff0000u);           \
        acc[4] += __uint_as_float(((rr).z & 0xffffu) << 16);       \
        acc[5] += __uint_as_float((rr).z & 0xffff0000u);           \
        acc[6] += __uint_as_float(((rr).w & 0xffffu) << 16);       \
        acc[7] += __uint_as_float((rr).w & 0xffff0000u);           \
    } while (0)

    for (int n = wv; n < SW; n += 8) {
        const int start = off_s[n];
        const int dg    = hist[n];
        const int end   = start + dg;

        float acc[8];
#pragma unroll
        for (int k = 0; k < 8; ++k) acc[k] = 0.0f;

        int j = start;
        for (; j + 15 < end; j += 16) {
            int s[4];
#pragma unroll
            for (int k = 0; k < 4; ++k) s[k] = csr_s[j + q + 4 * k];
            uint4 rg[4];
#pragma unroll
            for (int k = 0; k < 4; ++k)
                rg[k] = *reinterpret_cast<const uint4*>(h + (size_t)s[k] * 128 + sbl * 8);
#pragma unroll
            for (int k = 0; k < 4; ++k) UNPACK_ADD(rg[k]);
        }
        for (; j + 3 < end; j += 4) {
            const int s = csr_s[j + q];
            const uint4 rr = *reinterpret_cast<const uint4*>(h + (size_t)s * 128 + sbl * 8);
            UNPACK_ADD(rr);
        }
        const int rem = end - j;
        if (q < rem) {
            const int s = csr_s[j + q];
            const uint4 rr = *reinterpret_cast<const uint4*>(h + (size_t)s * 128 + sbl * 8);
            UNPACK_ADD(rr);
        }

#pragma unroll
        for (int k = 0; k < 8; ++k) {
            acc[k] += __shfl_xor(acc[k], 16, 64);
            acc[k] += __shfl_xor(acc[k], 32, 64);
        }

        if (lane < 16) {
            const float nm = rsqrtf(fmaxf((float)dg, 1.0f));
            const float4 b0 = *reinterpret_cast<const float4*>(bias + sbl * 8 + 0);
            const float4 b1 = *reinterpret_cast<const float4*>(bias + sbl * 8 + 4);
            float4 o0, o1;
            o0.x = fmaf(acc[0], nm, b0.x);
            o0.y = fmaf(acc[1], nm, b0.y);
            o0.z = fmaf(acc[2], nm, b0.z);
            o0.w = fmaf(acc[3], nm, b0.w);
            o1.x = fmaf(acc[4], nm, b1.x);
            o1.y = fmaf(acc[5], nm, b1.y);
            o1.z = fmaf(acc[6], nm, b1.z);
            o1.w = fmaf(acc[7], nm, b1.w);
            const size_t gnode = (size_t)(lo + nlo + n);
            *reinterpret_cast<float4*>(out + gnode * 128 + sbl * 8 + 0) = o0;
            *reinterpret_cast<float4*>(out + gnode * 128 + sbl * 8 + 4) = o1;
        }
    }
#undef UNPACK_ADD
}

// ---------- Fallback path (ws too small) ----------
__global__ void hist_simple(const int* __restrict__ dst, int* __restrict__ deg, int nE) {
    int e = blockIdx.x * blockDim.x + threadIdx.x;
    if (e < nE) atomicAdd(&deg[dst[e]], 1);
}
__global__ void bucket_simple(const int* __restrict__ src, const int* __restrict__ dst,
                              int* __restrict__ cur, int* __restrict__ csr, int nE) {
    int e = blockIdx.x * blockDim.x + threadIdx.x;
    if (e < nE) {
        int pos = atomicAdd(&cur[dst[e]], 1);
        csr[pos] = src[e];
    }
}
__global__ __launch_bounds__(256) void scan_chunks(const int* __restrict__ deg,
                                                   int* __restrict__ off,
                                                   int* __restrict__ partials, int N) {
    __shared__ int sums[256];
    const int b = blockIdx.x, t = threadIdx.x;
    const int base = b * CHUNK + t * 4;
    int v[4];
#pragma unroll
    for (int i = 0; i < 4; ++i) v[i] = (base + i < N) ? deg[base + i] : 0;
    const int s = v[0] + v[1] + v[2] + v[3];
    sums[t] = s;
    __syncthreads();
    for (int d = 1; d < 256; d <<= 1) {
        int x = (t >= d) ? sums[t - d] : 0;
        __syncthreads();
        sums[t] += x;
        __syncthreads();
    }
    const int excl = sums[t] - s;
    if (t == 255) partials[b] = sums[255];
    int run = excl;
#pragma unroll
    for (int i = 0; i < 4; ++i) {
        if (base + i < N) off[base + i] = run;
        run += v[i];
    }
}
__global__ __launch_bounds__(256) void scan_partials(int* partials, int P) {
    __shared__ int buf[256];
    const int t = threadIdx.x;
    if (P <= 256) {
        const int v = (t < P) ? partials[t] : 0;
        buf[t] = v;
        __syncthreads();
        for (int d = 1; d < 256; d <<= 1) {
            int x = (t >= d) ? buf[t - d] : 0;
            __syncthreads();
            buf[t] += x;
            __syncthreads();
        }
        if (t < P) partials[t] = buf[t] - v;
    } else if (t == 0) {
        int acc = 0;
        for (int i = 0; i < P; ++i) { int v = partials[i]; partials[i] = acc; acc += v; }
    }
}
__global__ void add_base(int* __restrict__ off, int* __restrict__ cur,
                         const int* __restrict__ partials, int N) {
    int i = blockIdx.x * blockDim.x + threadIdx.x;
    if (i < N) {
        int o = off[i] + partials[i >> 10];
        off[i] = o;
        cur[i] = o;
    }
}
__global__ __launch_bounds__(256) void aggregate_f32(const float* __restrict__ feat,
                                                     const int* __restrict__ csr,
                                                     const int* __restrict__ off,
                                                     const int* __restrict__ deg,
                                                     float* __restrict__ out, int N) {
    const int node = (blockIdx.x * blockDim.x + threadIdx.x) >> 6;
    if (node >= N) return;
    const int lane = threadIdx.x & 63;
    const int start = off[node];
    const int end   = start + deg[node];
    const float2* feat2 = reinterpret_cast<const float2*>(feat);
    float ax = 0.0f, ay = 0.0f;
    for (int j = start; j < end; ++j) {
        const float2 v = feat2[(size_t)csr[j] * 64 + lane];
        ax += v.x;
        ay += v.y;
    }
    reinterpret_cast<float2*>(out)[(size_t)node * 64 + lane] = make_float2(ax, ay);
}
__global__ __launch_bounds__(256) void gemm_norm(const float* agg,
                                                 const float* __restrict__ weight,
                                                 const float* __restrict__ bias,
                                                 const int* __restrict__ deg,
                                                 float* out, int M) {
    __shared__ float As[64][68];
    __shared__ float Wc[64][128];
    const int t  = threadIdx.x;
    const int tx = t & 15;
    const int ty = t >> 4;
    const int row0 = blockIdx.x * 64;
    float acc[4][8];
#pragma unroll
    for (int i = 0; i < 4; ++i)
#pragma unroll
        for (int j = 0; j < 8; ++j) acc[i][j] = 0.0f;
    for (int c = 0; c < 2; ++c) {
        if (c) __syncthreads();
        {
            const int k4 = (t & 15) * 4;
            const int rbase = t >> 4;
#pragma unroll
            for (int p = 0; p < 4; ++p) {
                const int rr = rbase + p * 16;
                const int grow = row0 + rr;
                float4 v = make_float4(0.f, 0.f, 0.f, 0.f);
                if (grow < M)
                    v = *reinterpret_cast<const float4*>(&agg[(size_t)grow * 128 + c * 64 + k4]);
                *reinterpret_cast<float4*>(&As[rr][k4]) = v;
            }
        }
        {
#pragma unroll
            for (int p = 0; p < 8; ++p) {
                const int idx = (p * 256 + t) * 4;
                const int kk = idx >> 7;
                const int j = idx & 127;
                *reinterpret_cast<float4*>(&Wc[kk][j]) =
                    *reinterpret_cast<const float4*>(&weight[(c * 64 + kk) * 128 + j]);
            }
        }
        __syncthreads();
#pragma unroll 8
        for (int k = 0; k < 64; ++k) {
            float a[4];
#pragma unroll
            for (int i = 0; i < 4; ++i) a[i] = As[ty * 4 + i][k];
            const float4 b0 = *reinterpret_cast<const float4*>(&Wc[k][tx * 8 + 0]);
            const float4 b1 = *reinterpret_cast<const float4*>(&Wc[k][tx * 8 + 4]);
            const float b[8] = {b0.x, b0.y, b0.z, b0.w, b1.x, b1.y, b1.z, b1.w};
#pragma unroll
            for (int i = 0; i < 4; ++i)
#pragma unroll
                for (int j = 0; j < 8; ++j)
                    acc[i][j] = fmaf(a[i], b[j], acc[i][j]);
        }
    }
    float bcol[8];
#pragma unroll
    for (int j = 0; j < 8; ++j) bcol[j] = bias[tx * 8 + j];
#pragma unroll
    for (int i = 0; i < 4; ++i) {
        const int grow = row0 + ty * 4 + i;
        if (grow < M) {
            const float nm = rsqrtf(fmaxf((float)deg[grow], 1.0f));
            float4 o0, o1;
            o0.x = fmaf(acc[i][0], nm, bcol[0]);
            o0.y = fmaf(acc[i][1], nm, bcol[1]);
            o0.z = fmaf(acc[i][2], nm, bcol[2]);
            o0.w = fmaf(acc[i][3], nm, bcol[3]);
            o1.x = fmaf(acc[i][4], nm, bcol[4]);
            o1.y = fmaf(acc[i][5], nm, bcol[5]);
            o1.z = fmaf(acc[i][6], nm, bcol[6]);
            o1.w = fmaf(acc[i][7], nm, bcol[7]);
            *reinterpret_cast<float4*>(&out[(size_t)grow * 128 + tx * 8 + 0]) = o0;
            *reinterpret_cast<float4*>(&out[(size_t)grow * 128 + tx * 8 + 4]) = o1;
        }
    }
}

extern "C" void kernel_launch(void* const* d_in, const int* in_sizes, int n_in,
                              void* d_out, int out_size, void* d_ws, size_t ws_size,
                              hipStream_t stream) {
    const float* feat   = (const float*)d_in[0];
    const int*   src    = (const int*)d_in[1];
    const int*   dst    = (const int*)d_in[2];
    const float* weight = (const float*)d_in[3];
    const float* bias   = (const float*)d_in[4];
    float* out = (float*)d_out;

    const int nE = in_sizes[1];
    const int M  = in_sizes[0] / 128;
    const int P  = (M + CHUNK - 1) / CHUNK;

    // main-path ws: gcur[RR] | wt[16384 ushort] | staging uint[RR*cap] | h ushort[M*128]
    int*    gcur    = (int*)d_ws;
    ushort* wt      = (ushort*)(gcur + RR);
    uint*   staging = (uint*)(wt + 16384);
    const int cap = (((nE + RR - 1) / RR + 8192) + 3) & ~3;
    ushort* h = (ushort*)(staging + (size_t)RR * cap);
    const size_t need = (size_t)RR * 4 + 32768 + (size_t)RR * cap * 4 + (size_t)M * 128 * 2;

    if (ws_size >= need && M <= 131072) {
        prep_w<<<64, 256, 0, stream>>>(weight, wt, gcur);
        gemm_mfma<<<(M + 63) / 64, 256, 0, stream>>>(feat, wt, h, M);
        partition64<<<1600, 256, 0, stream>>>(src, dst, gcur, staging, cap, nE, M);
        build_agg<<<RR * NSUB, 512, 0, stream>>>(staging, gcur, h, bias, out, cap, M);
    } else {
        int* degi     = (int*)d_ws;
        int* off      = degi + M;
        int* cur      = off + M;
        int* partials = cur + M;
        int* csr      = partials + 256;
        hipMemsetAsync(degi, 0, (size_t)M * sizeof(int), stream);
        hist_simple<<<(nE + 255) / 256, 256, 0, stream>>>(dst, degi, nE);
        scan_chunks<<<P, 256, 0, stream>>>(degi, off, partials, M);
        scan_partials<<<1, 256, 0, stream>>>(partials, P);
        add_base<<<(M + 255) / 256, 256, 0, stream>>>(off, cur, partials, M);
        bucket_simple<<<(nE + 255) / 256, 256, 0, stream>>>(src, dst, cur, csr, nE);
        aggregate_f32<<<(M + 3) / 4, 256, 0, stream>>>(feat, csr, off, degi, out, M);
        gemm_norm<<<(M + 63) / 64, 256, 0, stream>>>(out, weight, bias, degi, out, M);
    }
}